// Round 1
// 1217.916 us; speedup vs baseline: 1.3384x; 1.3384x over previous
//
#include <hip/hip_runtime.h>
#include <hip/hip_bf16.h>

// Problem constants (from reference)
#define N0 1000000
#define N1 102400
#define N2 10240
#define N3 1024
#define E0 1024000
#define E1 102400
#define E2 10240
#define D_IN 128
#define D_H 256
#define D_OUT 40

typedef float f4 __attribute__((ext_vector_type(4)));
typedef float f2 __attribute__((ext_vector_type(2)));

// ---------------- small utility kernels ----------------
__global__ void zero_ints(int* __restrict__ p, int n) {
    int i = blockIdx.x * blockDim.x + threadIdx.x;
    if (i < n) p[i] = 0;
}

__global__ void count_deg(const int* __restrict__ dst, int E, int* __restrict__ deg) {
    int e = blockIdx.x * blockDim.x + threadIdx.x;
    if (e < E) atomicAdd(&deg[dst[e]], 1);
}

// Block-level exclusive scan: each block covers 1024 elements (256 thr x 4).
__global__ __launch_bounds__(256)
void scan_blocks(const int* __restrict__ deg, int n,
                 int* __restrict__ rs, int* __restrict__ bsum) {
    __shared__ int s[256];
    int b = blockIdx.x, t = threadIdx.x;
    int base = b * 1024 + t * 4;
    int v[4]; int sum = 0;
    #pragma unroll
    for (int k = 0; k < 4; ++k) {
        int idx = base + k;
        v[k] = (idx < n) ? deg[idx] : 0;
        sum += v[k];
    }
    s[t] = sum; __syncthreads();
    for (int off = 1; off < 256; off <<= 1) {
        int x = (t >= off) ? s[t - off] : 0;
        __syncthreads();
        s[t] += x;
        __syncthreads();
    }
    int excl = s[t] - sum;
    #pragma unroll
    for (int k = 0; k < 4; ++k) {
        int idx = base + k;
        if (idx < n) rs[idx] = excl;
        excl += v[k];
    }
    if (t == 255) bsum[b] = s[255];
}

__global__ __launch_bounds__(256)
void scan_top(int* __restrict__ bsum, int nb) {
    __shared__ int s[256];
    int t = threadIdx.x;
    int v = (t < nb) ? bsum[t] : 0;
    s[t] = v; __syncthreads();
    for (int off = 1; off < 256; off <<= 1) {
        int x = (t >= off) ? s[t - off] : 0;
        __syncthreads();
        s[t] += x;
        __syncthreads();
    }
    if (t < nb) bsum[t] = s[t] - v;
}

__global__ void add_offsets(int* __restrict__ rs, int n, const int* __restrict__ bsum) {
    int i = blockIdx.x * blockDim.x + threadIdx.x;
    if (i < n) rs[i] += bsum[i >> 10];
}

__global__ void fill_edges(const int* __restrict__ src, const int* __restrict__ dst,
                           int E, int* __restrict__ rs, int* __restrict__ esrc) {
    int e = blockIdx.x * blockDim.x + threadIdx.x;
    if (e < E) {
        int pos = atomicAdd(&rs[dst[e]], 1);
        esrc[pos] = src[e];
    }
}

// ---------------- gather + mean: one wave per destination row ----------------
// float2 per lane: 64 lanes x 8B = 512B per instruction, fully coalesced.
template<int D>
__global__ __launch_bounds__(256)
void gather_mean(const float* __restrict__ h, const int* __restrict__ rs_after,
                 const int* __restrict__ esrc, float* __restrict__ aggr, int M) {
    int row  = blockIdx.x * (blockDim.x >> 6) + (threadIdx.x >> 6);
    int lane = threadIdx.x & 63;
    if (row >= M) return;
    int start = (row == 0) ? 0 : rs_after[row - 1];
    int end   = rs_after[row];
    constexpr int F = D / 128;          // float2 chunks per lane
    f2 acc[F] = {};
    int j = start;
    for (; j + 1 < end; j += 2) {
        int s0 = esrc[j], s1 = esrc[j + 1];
        const f2* p0 = (const f2*)(h + (size_t)s0 * D) + lane;
        const f2* p1 = (const f2*)(h + (size_t)s1 * D) + lane;
        #pragma unroll
        for (int f = 0; f < F; ++f) acc[f] += p0[f * 64] + p1[f * 64];
    }
    if (j < end) {
        int s0 = esrc[j];
        const f2* p0 = (const f2*)(h + (size_t)s0 * D) + lane;
        #pragma unroll
        for (int f = 0; f < F; ++f) acc[f] += p0[f * 64];
    }
    float inv = 1.0f / fmaxf((float)(end - start), 1.0f);
    f2* o = (f2*)(aggr + (size_t)row * D) + lane;
    #pragma unroll
    for (int f = 0; f < F; ++f) o[f * 64] = acc[f] * inv;
}

// ---------------- fused SAGE GEMM v2 ----------------
// out[i][j] = act( aggr[i].Wl[:,j] + bias[j] + htgt[i].Wr[:,j] )
// [aggr | htgt] (M x 2K) @ [[Wl],[Wr]] (2K x N), N == 256 == 2*BN.
// Requirements (hold for layers 0/1): M % BM == 0, K % 32 == 0, N % 128 == 0.
//
// 256 threads, thread grid 16(tx) x 16(ty). Per-thread tile:
//   rows: {h*64 + ty*4 + i : h<MH, i<4}, cols: {n*64 + tx*4 + j : n<2, j<4}
// Split 4+4 fragments => all LDS reads are ds_read_b128:
//   B-read addresses tx*16 (256B contiguous, 2-way = free);
//   A-read addresses ty*16 (broadcast across 16 lanes).
// As is stored k-major with +4 pad (keeps b128 reads 16B-aligned).
template<int BM, bool RELU>
__global__ __launch_bounds__(256, 4)
void sage_gemm_v2(const float* __restrict__ A0,  // aggr, M x K
                  const float* __restrict__ A1,  // htgt, M x K
                  const float* __restrict__ B0,  // Wl, K x N
                  const float* __restrict__ B1,  // Wr, K x N
                  const float* __restrict__ bias,
                  float* __restrict__ out,
                  int M, int N, int K) {
    constexpr int BK = 32;
    constexpr int BN = 128;
    constexpr int MH = BM / 64;           // row-halves per thread

    __shared__ float As[BK][BM + 4];      // transposed (k-major), padded
    __shared__ float Bs[BK][BN];          // k-major, n contiguous

    const int t   = threadIdx.x;
    const int tx4 = (t & 15) << 2;
    const int ty4 = (t >> 4) << 2;
    const int row0 = blockIdx.y * BM;
    const int col0 = blockIdx.x * BN;

    float acc[MH][4][2][4] = {};

    for (int half = 0; half < 2; ++half) {
        const float* __restrict__ Ap = half ? A1 : A0;
        const float* __restrict__ Bp = half ? B1 : B0;
        for (int k0 = 0; k0 < K; k0 += BK) {
            // ---- stage A (transposed) ----
            #pragma unroll
            for (int l = 0; l < BM / 32; ++l) {
                int fidx = l * 256 + t;          // float4 index
                int m  = fidx >> 3;              // row within tile
                int kq = (fidx & 7) << 2;        // k offset within tile
                f4 v = *(const f4*)&Ap[(size_t)(row0 + m) * K + k0 + kq];
                #pragma unroll
                for (int j = 0; j < 4; ++j) As[kq + j][m] = v[j];
            }
            // ---- stage B (direct) ----
            #pragma unroll
            for (int l = 0; l < 4; ++l) {
                int fidx = l * 256 + t;
                int kk = fidx >> 5;
                int c  = (fidx & 31) << 2;
                *(f4*)&Bs[kk][c] = *(const f4*)&Bp[(size_t)(k0 + kk) * N + col0 + c];
            }
            __syncthreads();

            #pragma unroll
            for (int kk = 0; kk < BK; ++kk) {
                f4 a[MH], b[2];
                #pragma unroll
                for (int h = 0; h < MH; ++h)
                    a[h] = *(const f4*)&As[kk][h * 64 + ty4];
                b[0] = *(const f4*)&Bs[kk][tx4];
                b[1] = *(const f4*)&Bs[kk][tx4 + 64];
                #pragma unroll
                for (int h = 0; h < MH; ++h)
                    #pragma unroll
                    for (int i = 0; i < 4; ++i)
                        #pragma unroll
                        for (int n = 0; n < 2; ++n)
                            #pragma unroll
                            for (int j = 0; j < 4; ++j)
                                acc[h][i][n][j] += a[h][i] * b[n][j];
            }
            __syncthreads();
        }
    }

    // ---- epilogue ----
    f4 bv0 = *(const f4*)&bias[col0 + tx4];
    f4 bv1 = *(const f4*)&bias[col0 + tx4 + 64];
    #pragma unroll
    for (int h = 0; h < MH; ++h) {
        #pragma unroll
        for (int i = 0; i < 4; ++i) {
            int r = row0 + h * 64 + ty4 + i;
            f4 v0, v1;
            #pragma unroll
            for (int j = 0; j < 4; ++j) {
                v0[j] = acc[h][i][0][j] + bv0[j];
                v1[j] = acc[h][i][1][j] + bv1[j];
                if (RELU) { v0[j] = fmaxf(v0[j], 0.f); v1[j] = fmaxf(v1[j], 0.f); }
            }
            *(f4*)&out[(size_t)r * N + col0 + tx4]      = v0;
            *(f4*)&out[(size_t)r * N + col0 + tx4 + 64] = v1;
        }
    }
}

// ---------------- generic tiled GEMM (kept for tiny layer 2, N=40) ----------------
#define TILE 64
#define BKK 32

template<bool RELU>
__global__ __launch_bounds__(256)
void sage_gemm(const float* __restrict__ aggr,
               const float* __restrict__ htgt,
               const float* __restrict__ Wl,
               const float* __restrict__ Wr,
               const float* __restrict__ bias,
               float* __restrict__ out,
               int M, int N, int K) {
    __shared__ float As[BKK][TILE + 1];
    __shared__ float Bs[BKK][TILE + 1];

    int tid = threadIdx.x;
    int row0 = blockIdx.y * TILE;
    int col0 = blockIdx.x * TILE;

    float acc[4][4] = {};
    int tx = tid & 15, ty = tid >> 4;

    int K2 = 2 * K;
    for (int k0 = 0; k0 < K2; k0 += BKK) {
        #pragma unroll
        for (int l = 0; l < (TILE * BKK) / 256; ++l) {
            int idx = l * 256 + tid;
            int kk = idx & (BKK - 1);
            int i  = idx / BKK;
            int kg = k0 + kk;
            int ig = row0 + i;
            float v = 0.f;
            if (ig < M) {
                if (kg < K) v = aggr[(size_t)ig * K + kg];
                else        v = htgt[(size_t)ig * K + (kg - K)];
            }
            As[kk][i] = v;
        }
        #pragma unroll
        for (int l = 0; l < (TILE * BKK) / 256; ++l) {
            int idx = l * 256 + tid;
            int j  = idx & (TILE - 1);
            int kk = idx / TILE;
            int kg = k0 + kk;
            int jg = col0 + j;
            float v = 0.f;
            if (jg < N) {
                if (kg < K) v = Wl[(size_t)kg * N + jg];
                else        v = Wr[(size_t)(kg - K) * N + jg];
            }
            Bs[kk][j] = v;
        }
        __syncthreads();

        #pragma unroll
        for (int kk = 0; kk < BKK; ++kk) {
            float a[4], b[4];
            #pragma unroll
            for (int m = 0; m < 4; ++m) a[m] = As[kk][ty + m * 16];
            #pragma unroll
            for (int n = 0; n < 4; ++n) b[n] = Bs[kk][tx + n * 16];
            #pragma unroll
            for (int m = 0; m < 4; ++m)
                #pragma unroll
                for (int n = 0; n < 4; ++n)
                    acc[m][n] += a[m] * b[n];
        }
        __syncthreads();
    }

    #pragma unroll
    for (int m = 0; m < 4; ++m) {
        int ig = row0 + ty + m * 16;
        if (ig >= M) continue;
        #pragma unroll
        for (int n = 0; n < 4; ++n) {
            int jg = col0 + tx + n * 16;
            if (jg >= N) continue;
            float v = acc[m][n] + bias[jg];
            if (RELU) v = fmaxf(v, 0.f);
            out[(size_t)ig * N + jg] = v;
        }
    }
}

// ---------------- log_softmax over rows of (M x N), N <= 64 ----------------
__global__ __launch_bounds__(256)
void log_softmax_kernel(float* __restrict__ out, int M, int N) {
    int row = blockIdx.x * (blockDim.x >> 6) + (threadIdx.x >> 6);
    int lane = threadIdx.x & 63;
    if (row >= M) return;
    float v = (lane < N) ? out[(size_t)row * N + lane] : -INFINITY;
    float m = v;
    #pragma unroll
    for (int off = 32; off; off >>= 1) m = fmaxf(m, __shfl_xor(m, off, 64));
    float e = (lane < N) ? expf(v - m) : 0.f;
    float s = e;
    #pragma unroll
    for (int off = 32; off; off >>= 1) s += __shfl_xor(s, off, 64);
    if (lane < N) out[(size_t)row * N + lane] = v - m - logf(s);
}

// ---------------- host-side orchestration ----------------
static void build_csr(const int* dst, int E, int n_tgt,
                      int* deg, int* rs, int* bsum, const int* src, int* esrc,
                      hipStream_t stream) {
    zero_ints<<<(n_tgt + 255) / 256, 256, 0, stream>>>(deg, n_tgt);
    count_deg<<<(E + 255) / 256, 256, 0, stream>>>(dst, E, deg);
    int nb = (n_tgt + 1023) / 1024;
    scan_blocks<<<nb, 256, 0, stream>>>(deg, n_tgt, rs, bsum);
    scan_top<<<1, 256, 0, stream>>>(bsum, nb);
    add_offsets<<<(n_tgt + 255) / 256, 256, 0, stream>>>(rs, n_tgt, bsum);
    fill_edges<<<(E + 255) / 256, 256, 0, stream>>>(src, dst, E, rs, esrc);
}

extern "C" void kernel_launch(void* const* d_in, const int* in_sizes, int n_in,
                              void* d_out, int out_size, void* d_ws, size_t ws_size,
                              hipStream_t stream) {
    const float* x    = (const float*)d_in[0];
    const int*   src0 = (const int*)d_in[1];
    const int*   dst0 = (const int*)d_in[2];
    const int*   src1 = (const int*)d_in[3];
    const int*   dst1 = (const int*)d_in[4];
    const int*   src2 = (const int*)d_in[5];
    const int*   dst2 = (const int*)d_in[6];
    const float* Wl0  = (const float*)d_in[7];
    const float* bl0  = (const float*)d_in[8];
    const float* Wr0  = (const float*)d_in[9];
    const float* Wl1  = (const float*)d_in[10];
    const float* bl1  = (const float*)d_in[11];
    const float* Wr1  = (const float*)d_in[12];
    const float* Wl2  = (const float*)d_in[13];
    const float* bl2  = (const float*)d_in[14];
    const float* Wr2  = (const float*)d_in[15];
    float* out = (float*)d_out;
    float* f   = (float*)d_ws;

    // Workspace layout (floats):
    //  [0, 13107200)            aggr0 (N1 x 128); region reused after gemm0 for:
    //       aggr1 [0, 2621440) | h2 [2621440, 5242880) | aggr2 [5242880, 5505024)
    //       esrc1 (E1 ints) at [5505024, ...) | esrc2 (E2 ints) after
    //  [13107200, 39321600)     h1 (N1 x 256); its head doubles as esrc0 (E0 ints)
    //                           BEFORE gemm0 writes h1 (stream-ordered, no overlap in time)
    //  [39321600, +2*N1+256)    int scratch: deg (N1) | rs (N1) | bsum (256)
    float* aggr0 = f;
    float* h1    = f + (size_t)13107200;
    int*   ib    = (int*)(f + (size_t)39321600);
    int* deg  = ib;
    int* rs   = ib + N1;
    int* bsum = ib + 2 * N1;
    int* esrc0 = (int*)h1;                       // alias: dead before gemm0 writes h1
    float* aggr1 = f;                            // after gemm0, aggr0 region is free
    float* h2    = f + (size_t)2621440;
    float* aggr2 = f + (size_t)5242880;
    int* esrc1 = (int*)(f + (size_t)5505024);
    int* esrc2 = (int*)(f + (size_t)5505024 + E1);

    // ---- Layer 0 ----  M=102400 (%128==0), K=128, N=256
    build_csr(dst0, E0, N1, deg, rs, bsum, src0, esrc0, stream);
    gather_mean<D_IN><<<(N1 + 3) / 4, 256, 0, stream>>>(x, rs, esrc0, aggr0, N1);
    sage_gemm_v2<128, true><<<dim3(D_H / 128, N1 / 128), 256, 0, stream>>>(
        aggr0, x, Wl0, Wr0, bl0, h1, N1, D_H, D_IN);

    // ---- Layer 1 ----  M=10240 (%64==0), K=256, N=256
    build_csr(dst1, E1, N2, deg, rs, bsum, src1, esrc1, stream);
    gather_mean<D_H><<<(N2 + 3) / 4, 256, 0, stream>>>(h1, rs, esrc1, aggr1, N2);
    sage_gemm_v2<64, true><<<dim3(D_H / 128, N2 / 64), 256, 0, stream>>>(
        aggr1, h1, Wl1, Wr1, bl1, h2, N2, D_H, D_H);

    // ---- Layer 2 ----  tiny (N=40): keep generic kernel
    build_csr(dst2, E2, N3, deg, rs, bsum, src2, esrc2, stream);
    gather_mean<D_H><<<(N3 + 3) / 4, 256, 0, stream>>>(h2, rs, esrc2, aggr2, N3);
    sage_gemm<false><<<dim3(1, N3 / TILE), 256, 0, stream>>>(
        aggr2, h2, Wl2, Wr2, bl2, out, N3, D_OUT, D_H);

    // ---- log_softmax ----
    log_softmax_kernel<<<(N3 + 3) / 4, 256, 0, stream>>>(out, N3, D_OUT);
}

// Round 2
// 1160.582 us; speedup vs baseline: 1.4045x; 1.0494x over previous
//
#include <hip/hip_runtime.h>
#include <hip/hip_bf16.h>

// Problem constants (from reference)
#define N0 1000000
#define N1 102400
#define N2 10240
#define N3 1024
#define E0 1024000
#define E1 102400
#define E2 10240
#define D_IN 128
#define D_H 256
#define D_OUT 40

#define NTOT (N1 + N2 + N3)   // 113664 rows across all layers
#define ETOT (E0 + E1 + E2)   // 1136640 edges across all layers

typedef float f4 __attribute__((ext_vector_type(4)));
typedef float f2 __attribute__((ext_vector_type(2)));

// ---------------- fused CSR build (all 3 layers in one global CSR) ----------------
// deg/rs are concatenated [layer0 (N1) | layer1 (N2) | layer2 (N3)].
// A single exclusive scan over the concatenation gives globally-correct edge
// offsets: layer1's first row starts exactly at E0, layer2's at E0+E1.

__global__ void zero_ints(int* __restrict__ p, int n) {
    int i = blockIdx.x * blockDim.x + threadIdx.x;
    if (i < n) p[i] = 0;
}

__global__ void count_deg_all(const int* __restrict__ d0, const int* __restrict__ d1,
                              const int* __restrict__ d2, int* __restrict__ deg) {
    int e = blockIdx.x * blockDim.x + threadIdx.x;
    if (e < E0)            atomicAdd(&deg[d0[e]], 1);
    else if (e < E0 + E1)  atomicAdd(&deg[N1 + d1[e - E0]], 1);
    else if (e < ETOT)     atomicAdd(&deg[N1 + N2 + d2[e - E0 - E1]], 1);
}

// Block-level exclusive scan: each block covers 1024 elements (256 thr x 4).
__global__ __launch_bounds__(256)
void scan_blocks(const int* __restrict__ deg, int n,
                 int* __restrict__ rs, int* __restrict__ bsum) {
    __shared__ int s[256];
    int b = blockIdx.x, t = threadIdx.x;
    int base = b * 1024 + t * 4;
    int v[4]; int sum = 0;
    #pragma unroll
    for (int k = 0; k < 4; ++k) {
        int idx = base + k;
        v[k] = (idx < n) ? deg[idx] : 0;
        sum += v[k];
    }
    s[t] = sum; __syncthreads();
    for (int off = 1; off < 256; off <<= 1) {
        int x = (t >= off) ? s[t - off] : 0;
        __syncthreads();
        s[t] += x;
        __syncthreads();
    }
    int excl = s[t] - sum;
    #pragma unroll
    for (int k = 0; k < 4; ++k) {
        int idx = base + k;
        if (idx < n) rs[idx] = excl;
        excl += v[k];
    }
    if (t == 255) bsum[b] = s[255];
}

__global__ __launch_bounds__(256)
void scan_top(int* __restrict__ bsum, int nb) {
    __shared__ int s[256];
    int t = threadIdx.x;
    int v = (t < nb) ? bsum[t] : 0;
    s[t] = v; __syncthreads();
    for (int off = 1; off < 256; off <<= 1) {
        int x = (t >= off) ? s[t - off] : 0;
        __syncthreads();
        s[t] += x;
        __syncthreads();
    }
    if (t < nb) bsum[t] = s[t] - v;
}

__global__ void add_offsets(int* __restrict__ rs, int n, const int* __restrict__ bsum) {
    int i = blockIdx.x * blockDim.x + threadIdx.x;
    if (i < n) rs[i] += bsum[i >> 10];
}

__global__ void fill_edges_all(const int* __restrict__ s0, const int* __restrict__ d0,
                               const int* __restrict__ s1, const int* __restrict__ d1,
                               const int* __restrict__ s2, const int* __restrict__ d2,
                               int* __restrict__ rs, int* __restrict__ esrc) {
    int e = blockIdx.x * blockDim.x + threadIdx.x;
    int sv, gr;
    if (e < E0)           { sv = s0[e];           gr = d0[e]; }
    else if (e < E0 + E1) { sv = s1[e - E0];      gr = N1 + d1[e - E0]; }
    else if (e < ETOT)    { sv = s2[e - E0 - E1]; gr = N1 + N2 + d2[e - E0 - E1]; }
    else return;
    int pos = atomicAdd(&rs[gr], 1);
    esrc[pos] = sv;
}

// ---------------- gather + mean: one wave per destination row ----------------
// rs_after points at the global rs array offset to this layer's first row.
// Row i start = rs_after[i-1]; for i==0: 0 (layer 0) or rs_after[-1] (later layers,
// which equals the previous layer's end — valid memory).
template<int D>
__global__ __launch_bounds__(256)
void gather_mean(const float* __restrict__ h, const int* __restrict__ rs_after,
                 const int* __restrict__ esrc, float* __restrict__ aggr,
                 int M, int has_prev) {
    int row  = blockIdx.x * (blockDim.x >> 6) + (threadIdx.x >> 6);
    int lane = threadIdx.x & 63;
    if (row >= M) return;
    int start = (row > 0) ? rs_after[row - 1] : (has_prev ? rs_after[-1] : 0);
    int end   = rs_after[row];
    constexpr int F = D / 128;          // float2 chunks per lane
    f2 acc[F] = {};
    int j = start;
    for (; j + 1 < end; j += 2) {
        int s0 = esrc[j], s1 = esrc[j + 1];
        const f2* p0 = (const f2*)(h + (size_t)s0 * D) + lane;
        const f2* p1 = (const f2*)(h + (size_t)s1 * D) + lane;
        #pragma unroll
        for (int f = 0; f < F; ++f) acc[f] += p0[f * 64] + p1[f * 64];
    }
    if (j < end) {
        int s0 = esrc[j];
        const f2* p0 = (const f2*)(h + (size_t)s0 * D) + lane;
        #pragma unroll
        for (int f = 0; f < F; ++f) acc[f] += p0[f * 64];
    }
    float inv = 1.0f / fmaxf((float)(end - start), 1.0f);
    f2* o = (f2*)(aggr + (size_t)row * D) + lane;
    #pragma unroll
    for (int f = 0; f < F; ++f) o[f * 64] = acc[f] * inv;
}

// ---------------- fused SAGE GEMM v2 (layers 0 and 1) ----------------
// out[i][j] = act( aggr[i].Wl[:,j] + bias[j] + htgt[i].Wr[:,j] )
// [aggr | htgt] (M x 2K) @ [[Wl],[Wr]] (2K x N), N == 256 == 2*BN.
// Requirements (hold for layers 0/1): M % BM == 0, K % 32 == 0, N % 128 == 0.
template<int BM, bool RELU>
__global__ __launch_bounds__(256, 4)
void sage_gemm_v2(const float* __restrict__ A0,  // aggr, M x K
                  const float* __restrict__ A1,  // htgt, M x K
                  const float* __restrict__ B0,  // Wl, K x N
                  const float* __restrict__ B1,  // Wr, K x N
                  const float* __restrict__ bias,
                  float* __restrict__ out,
                  int M, int N, int K) {
    constexpr int BK = 32;
    constexpr int BN = 128;
    constexpr int MH = BM / 64;           // row-halves per thread

    __shared__ float As[BK][BM + 4];      // transposed (k-major), padded
    __shared__ float Bs[BK][BN];          // k-major, n contiguous

    const int t   = threadIdx.x;
    const int tx4 = (t & 15) << 2;
    const int ty4 = (t >> 4) << 2;
    const int row0 = blockIdx.y * BM;
    const int col0 = blockIdx.x * BN;

    float acc[MH][4][2][4] = {};

    for (int half = 0; half < 2; ++half) {
        const float* __restrict__ Ap = half ? A1 : A0;
        const float* __restrict__ Bp = half ? B1 : B0;
        for (int k0 = 0; k0 < K; k0 += BK) {
            // ---- stage A (transposed) ----
            #pragma unroll
            for (int l = 0; l < BM / 32; ++l) {
                int fidx = l * 256 + t;          // float4 index
                int m  = fidx >> 3;              // row within tile
                int kq = (fidx & 7) << 2;        // k offset within tile
                f4 v = *(const f4*)&Ap[(size_t)(row0 + m) * K + k0 + kq];
                #pragma unroll
                for (int j = 0; j < 4; ++j) As[kq + j][m] = v[j];
            }
            // ---- stage B (direct) ----
            #pragma unroll
            for (int l = 0; l < 4; ++l) {
                int fidx = l * 256 + t;
                int kk = fidx >> 5;
                int c  = (fidx & 31) << 2;
                *(f4*)&Bs[kk][c] = *(const f4*)&Bp[(size_t)(k0 + kk) * N + col0 + c];
            }
            __syncthreads();

            #pragma unroll
            for (int kk = 0; kk < BK; ++kk) {
                f4 a[MH], b[2];
                #pragma unroll
                for (int h = 0; h < MH; ++h)
                    a[h] = *(const f4*)&As[kk][h * 64 + ty4];
                b[0] = *(const f4*)&Bs[kk][tx4];
                b[1] = *(const f4*)&Bs[kk][tx4 + 64];
                #pragma unroll
                for (int h = 0; h < MH; ++h)
                    #pragma unroll
                    for (int i = 0; i < 4; ++i)
                        #pragma unroll
                        for (int n = 0; n < 2; ++n)
                            #pragma unroll
                            for (int j = 0; j < 4; ++j)
                                acc[h][i][n][j] += a[h][i] * b[n][j];
            }
            __syncthreads();
        }
    }

    // ---- epilogue ----
    f4 bv0 = *(const f4*)&bias[col0 + tx4];
    f4 bv1 = *(const f4*)&bias[col0 + tx4 + 64];
    #pragma unroll
    for (int h = 0; h < MH; ++h) {
        #pragma unroll
        for (int i = 0; i < 4; ++i) {
            int r = row0 + h * 64 + ty4 + i;
            f4 v0, v1;
            #pragma unroll
            for (int j = 0; j < 4; ++j) {
                v0[j] = acc[h][i][0][j] + bv0[j];
                v1[j] = acc[h][i][1][j] + bv1[j];
                if (RELU) { v0[j] = fmaxf(v0[j], 0.f); v1[j] = fmaxf(v1[j], 0.f); }
            }
            *(f4*)&out[(size_t)r * N + col0 + tx4]      = v0;
            *(f4*)&out[(size_t)r * N + col0 + tx4 + 64] = v1;
        }
    }
}

// ---------------- layer 2: GEMM (N=40) + log_softmax, fused ----------------
// One wave per output row (grid 256 x 4 waves = 1024 rows). A row (aggr 256 +
// htgt 256 floats) lives in registers; W staged in LDS in two 40 KB passes.
// Lane j (<40) owns output column j; softmax is an in-wave shuffle reduce.
__global__ __launch_bounds__(256)
void sage_l2_softmax(const float* __restrict__ aggr,   // N3 x 256
                     const float* __restrict__ htgt,   // N3 x 256
                     const float* __restrict__ Wl,     // 256 x 40
                     const float* __restrict__ Wr,     // 256 x 40
                     const float* __restrict__ bias,   // 40
                     float* __restrict__ out) {        // N3 x 40
    __shared__ float Bs[D_H * D_OUT];   // 10240 floats = 40 KB
    const int t = threadIdx.x;
    const int wave = t >> 6, lane = t & 63;
    const int row = blockIdx.x * 4 + wave;   // grid = N3/4 = 256, always < N3

    float a[4], h[4];
    #pragma unroll
    for (int q = 0; q < 4; ++q) {
        a[q] = aggr[(size_t)row * D_H + q * 64 + lane];
        h[q] = htgt[(size_t)row * D_H + q * 64 + lane];
    }
    const int jc = (lane < D_OUT) ? lane : 0;   // clamp to avoid OOB LDS reads
    float acc = 0.f;
    constexpr int NF = (D_H * D_OUT) / 4;       // 2560 float4s

    // pass 1: aggr . Wl
    {
        const f4* w4 = (const f4*)Wl;
        f4* bs4 = (f4*)Bs;
        for (int i = t; i < NF; i += 256) bs4[i] = w4[i];
    }
    __syncthreads();
    #pragma unroll
    for (int q = 0; q < 4; ++q)
        for (int kk = 0; kk < 64; ++kk)
            acc += __shfl(a[q], kk, 64) * Bs[(q * 64 + kk) * D_OUT + jc];
    __syncthreads();

    // pass 2: htgt . Wr
    {
        const f4* w4 = (const f4*)Wr;
        f4* bs4 = (f4*)Bs;
        for (int i = t; i < NF; i += 256) bs4[i] = w4[i];
    }
    __syncthreads();
    #pragma unroll
    for (int q = 0; q < 4; ++q)
        for (int kk = 0; kk < 64; ++kk)
            acc += __shfl(h[q], kk, 64) * Bs[(q * 64 + kk) * D_OUT + jc];

    // bias + in-wave log_softmax
    float val = (lane < D_OUT) ? acc + bias[jc] : -INFINITY;
    float m = val;
    #pragma unroll
    for (int off = 32; off; off >>= 1) m = fmaxf(m, __shfl_xor(m, off, 64));
    float e = (lane < D_OUT) ? expf(val - m) : 0.f;
    float s = e;
    #pragma unroll
    for (int off = 32; off; off >>= 1) s += __shfl_xor(s, off, 64);
    if (lane < D_OUT) out[(size_t)row * D_OUT + lane] = val - m - logf(s);
}

// ---------------- host-side orchestration ----------------
extern "C" void kernel_launch(void* const* d_in, const int* in_sizes, int n_in,
                              void* d_out, int out_size, void* d_ws, size_t ws_size,
                              hipStream_t stream) {
    const float* x    = (const float*)d_in[0];
    const int*   src0 = (const int*)d_in[1];
    const int*   dst0 = (const int*)d_in[2];
    const int*   src1 = (const int*)d_in[3];
    const int*   dst1 = (const int*)d_in[4];
    const int*   src2 = (const int*)d_in[5];
    const int*   dst2 = (const int*)d_in[6];
    const float* Wl0  = (const float*)d_in[7];
    const float* bl0  = (const float*)d_in[8];
    const float* Wr0  = (const float*)d_in[9];
    const float* Wl1  = (const float*)d_in[10];
    const float* bl1  = (const float*)d_in[11];
    const float* Wr1  = (const float*)d_in[12];
    const float* Wl2  = (const float*)d_in[13];
    const float* bl2  = (const float*)d_in[14];
    const float* Wr2  = (const float*)d_in[15];
    float* out = (float*)d_out;
    float* f   = (float*)d_ws;

    // Workspace layout (floats):
    //  [0, 26214400)               h1 (N1 x 256)
    //  [26214400, 39321600)        aggr0 (N1 x 128); dead after gemm0, then reused:
    //      aggr1 [26214400, 28835840) | h2 [28835840, 31457280) | aggr2 [31457280, 31719424)
    //  [39321600, ...)             int scratch:
    //      esrc_all (ETOT=1136640) | deg (NTOT=113664) | rs (NTOT) | bsum (256)
    //  total ≈ 40.7M floats ≈ 163 MB
    float* h1    = f;
    float* aggr0 = f + (size_t)26214400;
    float* aggr1 = f + (size_t)26214400;    // reuse (aggr0 dead after gemm0)
    float* h2    = f + (size_t)28835840;
    float* aggr2 = f + (size_t)31457280;
    int* ib   = (int*)(f + (size_t)39321600);
    int* esrc = ib;
    int* deg  = ib + ETOT;
    int* rs   = ib + ETOT + NTOT;
    int* bsum = ib + ETOT + 2 * NTOT;

    // ---- global CSR build (all 3 layers, 6 dispatches) ----
    zero_ints<<<(NTOT + 255) / 256, 256, 0, stream>>>(deg, NTOT);
    count_deg_all<<<(ETOT + 255) / 256, 256, 0, stream>>>(dst0, dst1, dst2, deg);
    int nb = (NTOT + 1023) / 1024;   // 111
    scan_blocks<<<nb, 256, 0, stream>>>(deg, NTOT, rs, bsum);
    scan_top<<<1, 256, 0, stream>>>(bsum, nb);
    add_offsets<<<(NTOT + 255) / 256, 256, 0, stream>>>(rs, NTOT, bsum);
    fill_edges_all<<<(ETOT + 255) / 256, 256, 0, stream>>>(
        src0, dst0, src1, dst1, src2, dst2, rs, esrc);

    // ---- Layer 0 ----  M=102400, K=128, N=256
    gather_mean<D_IN><<<N1 / 4, 256, 0, stream>>>(x, rs, esrc, aggr0, N1, 0);
    sage_gemm_v2<128, true><<<dim3(D_H / 128, N1 / 128), 256, 0, stream>>>(
        aggr0, x, Wl0, Wr0, bl0, h1, N1, D_H, D_IN);

    // ---- Layer 1 ----  M=10240, K=256, N=256
    gather_mean<D_H><<<N2 / 4, 256, 0, stream>>>(h1, rs + N1, esrc, aggr1, N2, 1);
    sage_gemm_v2<64, true><<<dim3(D_H / 128, N2 / 64), 256, 0, stream>>>(
        aggr1, h1, Wl1, Wr1, bl1, h2, N2, D_H, D_H);

    // ---- Layer 2 + log_softmax (fused) ----
    gather_mean<D_H><<<N3 / 4, 256, 0, stream>>>(h2, rs + N1 + N2, esrc, aggr2, N3, 1);
    sage_l2_softmax<<<N3 / 4, 256, 0, stream>>>(aggr2, h2, Wl2, Wr2, bl2, out);
}

// Round 3
// 968.240 us; speedup vs baseline: 1.6835x; 1.1987x over previous
//
#include <hip/hip_runtime.h>
#include <hip/hip_bf16.h>

// Problem constants (from reference)
#define N0 1000000
#define N1 102400
#define N2 10240
#define N3 1024
#define E0 1024000
#define E1 102400
#define E2 10240
#define D_IN 128
#define D_H 256
#define D_OUT 40

#define NTOT (N1 + N2 + N3)   // 113664 rows across all layers
#define ETOT (E0 + E1 + E2)   // 1136640 edges across all layers

typedef float f4 __attribute__((ext_vector_type(4)));
typedef float f2 __attribute__((ext_vector_type(2)));
typedef unsigned short u16x8 __attribute__((ext_vector_type(8)));
typedef unsigned short u16x4 __attribute__((ext_vector_type(4)));
typedef short s16x8 __attribute__((ext_vector_type(8)));   // MFMA bf16 A/B frag (8 bf16)

static __device__ __forceinline__ unsigned short f2b(float x) {
    // f32 -> bf16 round-to-nearest-even (finite inputs)
    union { float f; unsigned u; } c; c.f = x;
    unsigned r = c.u + 0x7FFF + ((c.u >> 16) & 1);
    return (unsigned short)(r >> 16);
}
static __device__ __forceinline__ float b2f(unsigned short u) {
    union { unsigned u; float f; } c; c.u = (unsigned)u << 16;
    return c.f;
}

// ---------------- fused CSR build (all 3 layers in one global CSR) ----------------
__global__ void zero_ints(int* __restrict__ p, int n) {
    int i = blockIdx.x * blockDim.x + threadIdx.x;
    if (i < n) p[i] = 0;
}

__global__ void count_deg_all(const int* __restrict__ d0, const int* __restrict__ d1,
                              const int* __restrict__ d2, int* __restrict__ deg) {
    int e = blockIdx.x * blockDim.x + threadIdx.x;
    if (e < E0)            atomicAdd(&deg[d0[e]], 1);
    else if (e < E0 + E1)  atomicAdd(&deg[N1 + d1[e - E0]], 1);
    else if (e < ETOT)     atomicAdd(&deg[N1 + N2 + d2[e - E0 - E1]], 1);
}

__global__ __launch_bounds__(256)
void scan_blocks(const int* __restrict__ deg, int n,
                 int* __restrict__ rs, int* __restrict__ bsum) {
    __shared__ int s[256];
    int b = blockIdx.x, t = threadIdx.x;
    int base = b * 1024 + t * 4;
    int v[4]; int sum = 0;
    #pragma unroll
    for (int k = 0; k < 4; ++k) {
        int idx = base + k;
        v[k] = (idx < n) ? deg[idx] : 0;
        sum += v[k];
    }
    s[t] = sum; __syncthreads();
    for (int off = 1; off < 256; off <<= 1) {
        int x = (t >= off) ? s[t - off] : 0;
        __syncthreads();
        s[t] += x;
        __syncthreads();
    }
    int excl = s[t] - sum;
    #pragma unroll
    for (int k = 0; k < 4; ++k) {
        int idx = base + k;
        if (idx < n) rs[idx] = excl;
        excl += v[k];
    }
    if (t == 255) bsum[b] = s[255];
}

__global__ __launch_bounds__(256)
void scan_top(int* __restrict__ bsum, int nb) {
    __shared__ int s[256];
    int t = threadIdx.x;
    int v = (t < nb) ? bsum[t] : 0;
    s[t] = v; __syncthreads();
    for (int off = 1; off < 256; off <<= 1) {
        int x = (t >= off) ? s[t - off] : 0;
        __syncthreads();
        s[t] += x;
        __syncthreads();
    }
    if (t < nb) bsum[t] = s[t] - v;
}

__global__ void add_offsets(int* __restrict__ rs, int n, const int* __restrict__ bsum) {
    int i = blockIdx.x * blockDim.x + threadIdx.x;
    if (i < n) rs[i] += bsum[i >> 10];
}

__global__ void fill_edges_all(const int* __restrict__ s0, const int* __restrict__ d0,
                               const int* __restrict__ s1, const int* __restrict__ d1,
                               const int* __restrict__ s2, const int* __restrict__ d2,
                               int* __restrict__ rs, int* __restrict__ esrc) {
    int e = blockIdx.x * blockDim.x + threadIdx.x;
    int sv, gr;
    if (e < E0)           { sv = s0[e];           gr = d0[e]; }
    else if (e < E0 + E1) { sv = s1[e - E0];      gr = N1 + d1[e - E0]; }
    else if (e < ETOT)    { sv = s2[e - E0 - E1]; gr = N1 + N2 + d2[e - E0 - E1]; }
    else return;
    int pos = atomicAdd(&rs[gr], 1);
    esrc[pos] = sv;
}

// ---------------- weight prep: transpose to [N][K] + convert to bf16 ----------------
__global__ __launch_bounds__(256)
void prep_weights(const float* __restrict__ Wl0, const float* __restrict__ Wr0,
                  const float* __restrict__ Wl1, const float* __restrict__ Wr1,
                  unsigned short* __restrict__ Wt0l, unsigned short* __restrict__ Wt0r,
                  unsigned short* __restrict__ Wt1l, unsigned short* __restrict__ Wt1r) {
    int i = blockIdx.x * 256 + threadIdx.x;   // grid covers 65536
    if (i < D_IN * D_H) {        // Wl0/Wr0: [128][256] -> [256][128]
        int k = i >> 8, n = i & 255;
        Wt0l[n * D_IN + k] = f2b(Wl0[i]);
        Wt0r[n * D_IN + k] = f2b(Wr0[i]);
    }
    if (i < D_H * D_H) {         // Wl1/Wr1: [256][256] -> [256][256]
        int k = i >> 8, n = i & 255;
        Wt1l[n * D_H + k] = f2b(Wl1[i]);
        Wt1r[n * D_H + k] = f2b(Wr1[i]);
    }
}

// ---------------- gather + mean variants (one wave per destination row) ----------------
// Layer 0: f32 in (x, D=128), bf16 out (2 elems/lane packed as u32)
__global__ __launch_bounds__(256)
void gather_mean_f32_bf16(const float* __restrict__ h, const int* __restrict__ rs_after,
                          const int* __restrict__ esrc, unsigned* __restrict__ aggr,
                          int M) {
    int row  = blockIdx.x * (blockDim.x >> 6) + (threadIdx.x >> 6);
    int lane = threadIdx.x & 63;
    if (row >= M) return;
    int start = (row > 0) ? rs_after[row - 1] : 0;
    int end   = rs_after[row];
    f2 acc = {0.f, 0.f};
    int j = start;
    for (; j + 3 < end; j += 4) {
        int s0 = esrc[j], s1 = esrc[j + 1], s2 = esrc[j + 2], s3 = esrc[j + 3];
        acc += ((const f2*)(h + (size_t)s0 * D_IN))[lane];
        acc += ((const f2*)(h + (size_t)s1 * D_IN))[lane];
        acc += ((const f2*)(h + (size_t)s2 * D_IN))[lane];
        acc += ((const f2*)(h + (size_t)s3 * D_IN))[lane];
    }
    for (; j < end; ++j)
        acc += ((const f2*)(h + (size_t)esrc[j] * D_IN))[lane];
    float inv = 1.0f / fmaxf((float)(end - start), 1.0f);
    unsigned pack = (unsigned)f2b(acc.x * inv) | ((unsigned)f2b(acc.y * inv) << 16);
    aggr[(size_t)row * 64 + lane] = pack;
}

// Layer 1: bf16 in (h1, D=256), bf16 out (4 elems/lane, ushort4)
__global__ __launch_bounds__(256)
void gather_mean_bf16(const unsigned short* __restrict__ h, const int* __restrict__ rs_after,
                      const int* __restrict__ esrc, unsigned short* __restrict__ aggr,
                      int M) {
    int row  = blockIdx.x * (blockDim.x >> 6) + (threadIdx.x >> 6);
    int lane = threadIdx.x & 63;
    if (row >= M) return;
    int start = (row > 0) ? rs_after[row - 1] : rs_after[-1];
    int end   = rs_after[row];
    float acc[4] = {};
    for (int j = start; j < end; ++j) {
        const u16x4 v = *(const u16x4*)(h + (size_t)esrc[j] * D_H + lane * 4);
        #pragma unroll
        for (int q = 0; q < 4; ++q) acc[q] += b2f(v[q]);
    }
    float inv = 1.0f / fmaxf((float)(end - start), 1.0f);
    u16x4 o;
    #pragma unroll
    for (int q = 0; q < 4; ++q) o[q] = f2b(acc[q] * inv);
    *(u16x4*)(aggr + (size_t)row * D_H + lane * 4) = o;
}

// Layer 2: f32 in (h2, D=256), f32 out
__global__ __launch_bounds__(256)
void gather_mean_f32(const float* __restrict__ h, const int* __restrict__ rs_after,
                     const int* __restrict__ esrc, float* __restrict__ aggr, int M) {
    int row  = blockIdx.x * (blockDim.x >> 6) + (threadIdx.x >> 6);
    int lane = threadIdx.x & 63;
    if (row >= M) return;
    int start = (row > 0) ? rs_after[row - 1] : rs_after[-1];
    int end   = rs_after[row];
    f2 acc[2] = {};
    for (int j = start; j < end; ++j) {
        const f2* p = (const f2*)(h + (size_t)esrc[j] * D_H) + lane;
        acc[0] += p[0];
        acc[1] += p[64];
    }
    float inv = 1.0f / fmaxf((float)(end - start), 1.0f);
    f2* o = (f2*)(aggr + (size_t)row * D_H) + lane;
    o[0]  = acc[0] * inv;
    o[64] = acc[1] * inv;
}

// ---------------- bf16 MFMA SAGE GEMM (layers 0 and 1) ----------------
// out[i][j] = act( aggr[i].Wl[:,j] + bias[j] + htgt[i].Wr[:,j] ), N fixed = 256.
// Tile: BM=64, BN=256, BK=32. 4 waves; wave w owns cols [w*64, w*64+64).
// A0 = aggr (bf16 [M][K]); A1 = htgt (f32 [M][K] if A1F32, else bf16).
// Bl/Br = weights pre-transposed bf16 [N=256][K].
// MFMA 16x16x32 bf16: A frag lane l holds A[m=l&15][k=(l>>4)*8 + 0..7];
//                     B frag lane l holds B[k=(l>>4)*8 + 0..7][n=l&15];
//                     D: col=l&15, row=(l>>4)*4+reg  (m89-verified layout).
// LDS rows padded to 40 ushorts (80 B = 20 banks): b128 reads are ~2-way (free).
template<bool A1F32, bool RELU, bool OUTBF16>
__global__ __launch_bounds__(256)
void sage_gemm_mfma(const unsigned short* __restrict__ A0,
                    const void* __restrict__ A1,
                    const unsigned short* __restrict__ Bl,
                    const unsigned short* __restrict__ Br,
                    const float* __restrict__ bias,
                    void* __restrict__ out,
                    int M, int K) {
    __shared__ unsigned short As[64][40];
    __shared__ unsigned short Bs[256][40];

    const int t = threadIdx.x;
    const int lane = t & 63;
    const int w = t >> 6;
    const int row0 = blockIdx.x * 64;

    const int lrow = lane & 15;
    const int kq   = (lane >> 4) * 8;

    f4 acc[4][4] = {};

    // staging indices
    const int ar = t >> 2;            // A row 0..63
    const int ac = (t & 3) * 8;       // A k-chunk

    #pragma unroll
    for (int half = 0; half < 2; ++half) {
        const unsigned short* __restrict__ Bp = half ? Br : Bl;
        for (int k0 = 0; k0 < K; k0 += 32) {
            // ---- stage A ----
            {
                size_t gidx = (size_t)(row0 + ar) * K + k0 + ac;
                u16x8 v;
                if (half == 0) {
                    v = *(const u16x8*)(A0 + gidx);
                } else if (!A1F32) {
                    v = *(const u16x8*)((const unsigned short*)A1 + gidx);
                } else {
                    const float* p = (const float*)A1 + gidx;
                    f4 x0 = *(const f4*)p;
                    f4 x1 = *(const f4*)(p + 4);
                    v[0] = f2b(x0[0]); v[1] = f2b(x0[1]); v[2] = f2b(x0[2]); v[3] = f2b(x0[3]);
                    v[4] = f2b(x1[0]); v[5] = f2b(x1[1]); v[6] = f2b(x1[2]); v[7] = f2b(x1[3]);
                }
                *(u16x8*)&As[ar][ac] = v;
            }
            // ---- stage B ----
            #pragma unroll
            for (int i = 0; i < 4; ++i) {
                int idx = i * 256 + t;
                int n = idx >> 2, c = (idx & 3) * 8;
                *(u16x8*)&Bs[n][c] = *(const u16x8*)(Bp + (size_t)n * K + k0 + c);
            }
            __syncthreads();

            // ---- fragments + MFMA ----
            s16x8 a[4], b[4];
            #pragma unroll
            for (int mf = 0; mf < 4; ++mf)
                a[mf] = *(const s16x8*)&As[mf * 16 + lrow][kq];
            #pragma unroll
            for (int nf = 0; nf < 4; ++nf)
                b[nf] = *(const s16x8*)&Bs[w * 64 + nf * 16 + lrow][kq];
            #pragma unroll
            for (int mf = 0; mf < 4; ++mf)
                #pragma unroll
                for (int nf = 0; nf < 4; ++nf)
                    acc[mf][nf] = __builtin_amdgcn_mfma_f32_16x16x32_bf16(
                        a[mf], b[nf], acc[mf][nf], 0, 0, 0);
            __syncthreads();
        }
    }

    // ---- epilogue ----
    const int crow = (lane >> 4) * 4;
    const int ccol = lane & 15;
    float bv[4];
    #pragma unroll
    for (int nf = 0; nf < 4; ++nf) bv[nf] = bias[w * 64 + nf * 16 + ccol];

    #pragma unroll
    for (int mf = 0; mf < 4; ++mf) {
        #pragma unroll
        for (int nf = 0; nf < 4; ++nf) {
            int c = w * 64 + nf * 16 + ccol;
            #pragma unroll
            for (int rg = 0; rg < 4; ++rg) {
                int r = row0 + mf * 16 + crow + rg;
                float v = acc[mf][nf][rg] + bv[nf];
                if (RELU) v = fmaxf(v, 0.f);
                if (OUTBF16)
                    ((unsigned short*)out)[(size_t)r * 256 + c] = f2b(v);
                else
                    ((float*)out)[(size_t)r * 256 + c] = v;
            }
        }
    }
}

// ---------------- layer 2: GEMM (N=40) + log_softmax, fused (all f32) ----------------
__global__ __launch_bounds__(256)
void sage_l2_softmax(const float* __restrict__ aggr,   // N3 x 256
                     const float* __restrict__ htgt,   // N3 x 256
                     const float* __restrict__ Wl,     // 256 x 40
                     const float* __restrict__ Wr,     // 256 x 40
                     const float* __restrict__ bias,   // 40
                     float* __restrict__ out) {        // N3 x 40
    __shared__ float Bs[D_H * D_OUT];   // 40 KB
    const int t = threadIdx.x;
    const int wave = t >> 6, lane = t & 63;
    const int row = blockIdx.x * 4 + wave;

    float a[4], h[4];
    #pragma unroll
    for (int q = 0; q < 4; ++q) {
        a[q] = aggr[(size_t)row * D_H + q * 64 + lane];
        h[q] = htgt[(size_t)row * D_H + q * 64 + lane];
    }
    const int jc = (lane < D_OUT) ? lane : 0;
    float acc = 0.f;
    constexpr int NF = (D_H * D_OUT) / 4;

    {
        const f4* w4 = (const f4*)Wl;
        f4* bs4 = (f4*)Bs;
        for (int i = t; i < NF; i += 256) bs4[i] = w4[i];
    }
    __syncthreads();
    #pragma unroll
    for (int q = 0; q < 4; ++q)
        for (int kk = 0; kk < 64; ++kk)
            acc += __shfl(a[q], kk, 64) * Bs[(q * 64 + kk) * D_OUT + jc];
    __syncthreads();

    {
        const f4* w4 = (const f4*)Wr;
        f4* bs4 = (f4*)Bs;
        for (int i = t; i < NF; i += 256) bs4[i] = w4[i];
    }
    __syncthreads();
    #pragma unroll
    for (int q = 0; q < 4; ++q)
        for (int kk = 0; kk < 64; ++kk)
            acc += __shfl(h[q], kk, 64) * Bs[(q * 64 + kk) * D_OUT + jc];

    float val = (lane < D_OUT) ? acc + bias[jc] : -INFINITY;
    float m = val;
    #pragma unroll
    for (int off = 32; off; off >>= 1) m = fmaxf(m, __shfl_xor(m, off, 64));
    float e = (lane < D_OUT) ? expf(val - m) : 0.f;
    float s = e;
    #pragma unroll
    for (int off = 32; off; off >>= 1) s += __shfl_xor(s, off, 64);
    if (lane < D_OUT) out[(size_t)row * D_OUT + lane] = val - m - logf(s);
}

// ---------------- host-side orchestration ----------------
extern "C" void kernel_launch(void* const* d_in, const int* in_sizes, int n_in,
                              void* d_out, int out_size, void* d_ws, size_t ws_size,
                              hipStream_t stream) {
    const float* x    = (const float*)d_in[0];
    const int*   src0 = (const int*)d_in[1];
    const int*   dst0 = (const int*)d_in[2];
    const int*   src1 = (const int*)d_in[3];
    const int*   dst1 = (const int*)d_in[4];
    const int*   src2 = (const int*)d_in[5];
    const int*   dst2 = (const int*)d_in[6];
    const float* Wl0  = (const float*)d_in[7];
    const float* bl0  = (const float*)d_in[8];
    const float* Wr0  = (const float*)d_in[9];
    const float* Wl1  = (const float*)d_in[10];
    const float* bl1  = (const float*)d_in[11];
    const float* Wr1  = (const float*)d_in[12];
    const float* Wl2  = (const float*)d_in[13];
    const float* bl2  = (const float*)d_in[14];
    const float* Wr2  = (const float*)d_in[15];
    float* out = (float*)d_out;
    float* f   = (float*)d_ws;

    // Workspace layout (float units):
    //  h1b   (bf16 N1x256)  [0, 13107200)
    //  aggr0b(bf16 N1x128)  [13107200, 19660800)
    //  aggr1b(bf16 N2x256)  [19660800, 20971520)
    //  h2    (f32  N2x256)  [20971520, 23592960)
    //  aggr2 (f32  N3x256)  [23592960, 23855104)
    //  Wt0l/Wt0r (bf16 256x128) [23855104, +16384) / +16384
    //  Wt1l/Wt1r (bf16 256x256) next, +32768 each -> ends 23953408
    //  ints: esrc (ETOT) | deg (NTOT) | rs (NTOT) | bsum (256)
    unsigned short* h1b    = (unsigned short*)f;
    unsigned short* aggr0b = (unsigned short*)(f + (size_t)13107200);
    unsigned short* aggr1b = (unsigned short*)(f + (size_t)19660800);
    float* h2    = f + (size_t)20971520;
    float* aggr2 = f + (size_t)23592960;
    unsigned short* Wt0l = (unsigned short*)(f + (size_t)23855104);
    unsigned short* Wt0r = Wt0l + 32768;
    unsigned short* Wt1l = Wt0r + 32768;
    unsigned short* Wt1r = Wt1l + 65536;
    int* ib   = (int*)(f + (size_t)23953408);
    int* esrc = ib;
    int* deg  = ib + ETOT;
    int* rs   = ib + ETOT + NTOT;
    int* bsum = ib + ETOT + 2 * NTOT;

    // ---- weight prep (independent) ----
    prep_weights<<<256, 256, 0, stream>>>(Wl0, Wr0, Wl1, Wr1, Wt0l, Wt0r, Wt1l, Wt1r);

    // ---- global CSR build ----
    zero_ints<<<(NTOT + 255) / 256, 256, 0, stream>>>(deg, NTOT);
    count_deg_all<<<(ETOT + 255) / 256, 256, 0, stream>>>(dst0, dst1, dst2, deg);
    int nb = (NTOT + 1023) / 1024;   // 111
    scan_blocks<<<nb, 256, 0, stream>>>(deg, NTOT, rs, bsum);
    scan_top<<<1, 256, 0, stream>>>(bsum, nb);
    add_offsets<<<(NTOT + 255) / 256, 256, 0, stream>>>(rs, NTOT, bsum);
    fill_edges_all<<<(ETOT + 255) / 256, 256, 0, stream>>>(
        src0, dst0, src1, dst1, src2, dst2, rs, esrc);

    // ---- Layer 0 ----  M=102400, K=128
    gather_mean_f32_bf16<<<N1 / 4, 256, 0, stream>>>(x, rs, esrc, (unsigned*)aggr0b, N1);
    sage_gemm_mfma<true, true, true><<<N1 / 64, 256, 0, stream>>>(
        aggr0b, x, Wt0l, Wt0r, bl0, h1b, N1, D_IN);

    // ---- Layer 1 ----  M=10240, K=256
    gather_mean_bf16<<<N2 / 4, 256, 0, stream>>>(h1b, rs + N1, esrc, aggr1b, N2);
    sage_gemm_mfma<false, true, false><<<N2 / 64, 256, 0, stream>>>(
        aggr1b, h1b, Wt1l, Wt1r, bl1, h2, N2, D_H);

    // ---- Layer 2 + log_softmax (all f32) ----
    gather_mean_f32<<<N3 / 4, 256, 0, stream>>>(h2, rs + N1 + N2, esrc, aggr2, N3);
    sage_l2_softmax<<<N3 / 4, 256, 0, stream>>>(aggr2, h2, Wl2, Wr2, bl2, out);
}